// Round 2
// baseline (401.974 us; speedup 1.0000x reference)
//
#include <hip/hip_runtime.h>

#define DIMC 512
#define NTOK 4097
#define GH 64
#define GW 64
#define TH 16

// Fold w7 + padded(w5) + padded(w3) + identity into one 7x7 depthwise kernel,
// stored tap-major [t][c] so lanes (channels) read coalesced. Bias = b7+b5+b3.
__global__ __launch_bounds__(256) void prep_kernel(
    const float* __restrict__ w7, const float* __restrict__ b7,
    const float* __restrict__ w5, const float* __restrict__ b5,
    const float* __restrict__ w3, const float* __restrict__ b3,
    float* __restrict__ wc, float* __restrict__ bc)
{
    int idx = blockIdx.x * 256 + threadIdx.x;   // 0 .. 512*49-1
    if (idx < DIMC * 49) {
        int c = idx & (DIMC - 1);
        int t = idx >> 9;
        int dy = t / 7, dx = t - dy * 7;
        float v = w7[c * 49 + t];
        if (dy >= 1 && dy <= 5 && dx >= 1 && dx <= 5)
            v += w5[c * 25 + (dy - 1) * 5 + (dx - 1)];
        if (dy >= 2 && dy <= 4 && dx >= 2 && dx <= 4)
            v += w3[c * 9 + (dy - 2) * 3 + (dx - 2)];
        if (dy == 3 && dx == 3) v += 1.0f;      // identity (residual) term
        wc[t * DIMC + c] = v;
    }
    if (idx < DIMC) bc[idx] = b7[idx] + b5[idx] + b3[idx];
}

// cls token pass-through: out[b,0,:] = x[b,0,:]
__global__ __launch_bounds__(256) void cls_kernel(
    const float* __restrict__ x, float* __restrict__ out)
{
    int i = blockIdx.x * 256 + threadIdx.x;     // 0 .. 16*512-1
    int b = i >> 9, c = i & 511;
    size_t off = (size_t)b * NTOK * DIMC + c;
    out[off] = x[off];
}

// Depthwise combined 7x7 conv, channels on lanes, 4 output columns per thread.
// Streams input rows: each row is loaded once into a 10-wide double-buffered
// register row and accumulated into a 7-deep ring of per-output-row partials
// (dx-sharing: 10 loads serve 4 output columns -> 3.4 loads/output vs 9.6).
__global__ __launch_bounds__(256) void dwconv_kernel(
    const float* __restrict__ x, const float* __restrict__ wc,
    const float* __restrict__ bc, float* __restrict__ out)
{
    const int lane = threadIdx.x;                  // 0..63 = channel in chunk
    const int wv   = threadIdx.y;                  // 0..3  = wave id
    const int wseg = blockIdx.x;                   // 0..3
    const int yid  = blockIdx.y;                   // 0..31 = cseg(8) x hseg(4)
    const int b    = blockIdx.z;                   // 0..15
    const int cc = (yid >> 2) * 64 + lane;         // channel 0..511
    const int h0 = (yid & 3) * TH;                 // output row base
    const int w0 = (wseg * 4 + wv) * 4;            // first of 4 output columns

    float wgt[49];
#pragma unroll
    for (int t = 0; t < 49; ++t) wgt[t] = wc[t * DIMC + cc];
    const float bias = bc[cc];

    const float* __restrict__ xin = x   + ((size_t)b * NTOK + 1) * DIMC + cc;
    float* __restrict__ op        = out + ((size_t)b * NTOK + 1) * DIMC + cc;

    float acc[7][4];    // ring of output-row partials, slot = j % 7
    float buf[2][10];   // double-buffered input row (cols w0-3 .. w0+6)

    auto load_row = [&](int r, float (&row)[10]) {
        if (r < 0 || r >= GH) {
#pragma unroll
            for (int i = 0; i < 10; ++i) row[i] = 0.0f;
        } else {
            const float* rp = xin + (size_t)r * GW * DIMC;
#pragma unroll
            for (int i = 0; i < 10; ++i) {
                int ci = w0 - 3 + i;               // wave-uniform guard
                row[i] = (ci >= 0 && ci < GW) ? rp[(size_t)ci * DIMC] : 0.0f;
            }
        }
    };

    load_row(h0 - 3, buf[0]);

#pragma unroll
    for (int k = 0; k < TH + 6; ++k) {             // input row r = h0-3+k
        float (&cur)[10] = buf[k & 1];
        if (k + 1 < TH + 6) load_row(h0 - 3 + (k + 1), buf[(k + 1) & 1]);

        // newly-activated output row j = k (first contribution, dy=0)
        if (k <= TH - 1) {
#pragma unroll
            for (int c = 0; c < 4; ++c) acc[k % 7][c] = bias;
        }

        // active output rows j with dy = k - j in [0,6]
#pragma unroll
        for (int j = 0; j < TH; ++j) {
            if (j >= ((k - 6 < 0) ? 0 : k - 6) && j <= ((k < TH - 1) ? k : TH - 1)) {
                const int dy = k - j;
#pragma unroll
                for (int c = 0; c < 4; ++c) {
#pragma unroll
                    for (int dx = 0; dx < 7; ++dx)
                        acc[j % 7][c] += wgt[dy * 7 + dx] * cur[c + dx];
                }
            }
        }

        // completed output row j = k - 6 (just received its dy=6 term)
        if (k >= 6) {
            const int j = k - 6;
            const int o = h0 + j;
#pragma unroll
            for (int c = 0; c < 4; ++c)
                op[((size_t)o * GW + (w0 + c)) * DIMC] = acc[j % 7][c];
        }
    }
}

extern "C" void kernel_launch(void* const* d_in, const int* in_sizes, int n_in,
                              void* d_out, int out_size, void* d_ws, size_t ws_size,
                              hipStream_t stream)
{
    const float* x  = (const float*)d_in[0];
    const float* w7 = (const float*)d_in[1];
    const float* b7 = (const float*)d_in[2];
    const float* w5 = (const float*)d_in[3];
    const float* b5 = (const float*)d_in[4];
    const float* w3 = (const float*)d_in[5];
    const float* b3 = (const float*)d_in[6];
    float* out = (float*)d_out;
    float* wcomb = (float*)d_ws;            // 49*512 floats
    float* bcomb = wcomb + 49 * DIMC;       // 512 floats

    prep_kernel<<<98, 256, 0, stream>>>(w7, b7, w5, b5, w3, b3, wcomb, bcomb);
    cls_kernel<<<32, 256, 0, stream>>>(x, out);

    dim3 grid(4, 32, 16);                   // wseg x (cseg*4+hseg) x batch
    dim3 block(64, 4, 1);                   // 64 channel-lanes x 4 waves
    dwconv_kernel<<<grid, block, 0, stream>>>(x, wcomb, bcomb, out);
}